// Round 7
// baseline (119.840 us; speedup 1.0000x reference)
//
#include <hip/hip_runtime.h>
#include <math.h>

typedef __attribute__((ext_vector_type(8))) short bf16x8;
typedef __attribute__((ext_vector_type(4))) float f32x4;
typedef __attribute__((ext_vector_type(4))) unsigned int u32x4;
typedef __attribute__((ext_vector_type(2))) unsigned int u32x2;

namespace {
constexpr int OUT0 = 2 * 32 * 16384;  // offset of att_mp inside d_out
constexpr int NPIX = 32768;           // total pixels (both batches)
}

// f32 -> bf16 RNE (pre-shift: result in high 16 bits)
__device__ __forceinline__ unsigned int bf16_rne(float f) {
  unsigned int u = __builtin_bit_cast(unsigned int, f);
  return u + 0x7fffu + ((u >> 16) & 1u);
}
// f32 -> bf16 round-half-up (1 VALU; tie-bias only)
__device__ __forceinline__ unsigned int bf16_rhu(float f) {
  return __builtin_bit_cast(unsigned int, f) + 0x8000u;
}
__device__ __forceinline__ unsigned int pack_rne(float lo, float hi) {
  return __builtin_amdgcn_perm(bf16_rne(hi), bf16_rne(lo), 0x07060302u);
}
__device__ __forceinline__ unsigned int pack_rhu(float lo, float hi) {
  return __builtin_amdgcn_perm(bf16_rhu(hi), bf16_rhu(lo), 0x07060302u);
}
__device__ __forceinline__ float bf16_to_f32(unsigned int u16v) {
  return __builtin_bit_cast(float, u16v << 16);
}

// Prep: (a) pack w3 into per-lane bf16 B-fragments for mfma_f32_16x16x32_bf16:
//   u32x4 index = ij*128 + oh*64 + lane; dword d: B[k0][o],B[k0+1][o],
//   k(=c) = (lane>>4)*8 + 2d, o = oh*16 + (lane&15).
// (b) wk[c*9+dd] = sum_o w2[o]*w1[o,c,dd]; wk[288] = w2.b1 + b2.
__global__ __launch_bounds__(256) void prep_kernel(
    const float* __restrict__ w1, const float* __restrict__ b1,
    const float* __restrict__ w2, const float* __restrict__ b2,
    const float* __restrict__ w3,
    float* __restrict__ wk, unsigned int* __restrict__ w3f) {
  int t = threadIdx.x, blk = blockIdx.x;
  if (blk < 98) {
    int f = blk * 256 + t;          // dword index, f < 25088
    int d = f & 3;
    int lane = (f >> 2) & 63;
    int nt = (f >> 8) & 1;
    int ij = f >> 9;                // 0..48
    int o = nt * 16 + (lane & 15);
    int k0 = ((lane >> 4) << 3) + 2 * d;
    float f0 = w3[o * 1568 + k0 * 49 + ij];
    float f1 = w3[o * 1568 + (k0 + 1) * 49 + ij];
    w3f[f] = pack_rne(f0, f1);
  } else {
    int k = (blk - 98) * 256 + t;
    if (k < 288) {
      int c = k / 9, r = k - c * 9;
      float s = 0.f;
#pragma unroll
      for (int o = 0; o < 32; ++o) s += w2[o] * w1[o * 288 + c * 9 + r];
      wk[k] = s;
    } else if (k == 288) {
      float s = b2[0];
#pragma unroll
      for (int o = 0; o < 32; ++o) s += w2[o] * b1[o];
      wk[288] = s;
    }
  }
}

// att kernel: one 8x8 tile per block (512 blocks x 256 threads).
// Produces: att_out (n-major), gt[ij][n] = 1+att (tap-major), xt[n][c] bf16.
__global__ __launch_bounds__(256) void att_kernel(
    const float* __restrict__ x, const float* __restrict__ wk,
    float* __restrict__ att_out, float* __restrict__ gt,
    unsigned int* __restrict__ xt) {
  __shared__ __align__(16) char regA[16384];
  unsigned short* xs16 = (unsigned short*)regA;   // bf16 planar [c*256+sp]
  float* as_ = (float*)regA;                      // g-tile [pos*68+px] (aliased)
  __shared__ unsigned short ysb[9 * 224];         // bf16 y[dd][(r-1)*16+cc]
  __shared__ float wks[289];

  int t = threadIdx.x;
  int bi = blockIdx.x;
  int b = bi >> 8;
  int tile = bi & 255;
  int y0 = (tile >> 4) << 3, x0 = (tile & 15) << 3;
  const float* xb = x + ((long)b << 19);

  for (int k = t; k < 289; k += 256) wks[k] = wk[k];

  // ---- phase 1: global f32x4 -> bf16 -> planar xs16 (conflict-free b64) ----
#pragma unroll
  for (int it = 0; it < 8; ++it) {
    int idx = it * 256 + t;
    int c = idx >> 6;
    int r64 = idx & 63;
    int row = r64 >> 2, seg = r64 & 3;
    int gy = y0 + row - 4;
    int gxs = x0 + (seg << 2) - 4;
    f32x4 v = {0.f, 0.f, 0.f, 0.f};
    if ((unsigned)gy < 128u && (unsigned)gxs < 128u)
      v = *reinterpret_cast<const f32x4*>(xb + (c << 14) + (gy << 7) + gxs);
    u32x2 p;
    p[0] = pack_rhu(v[0], v[1]);
    p[1] = pack_rhu(v[2], v[3]);
    *reinterpret_cast<u32x2*>(reinterpret_cast<unsigned int*>(xs16) +
                              (c << 7) + (r64 << 1)) = p;
  }
  __syncthreads();

  // ---- phase 1b (thread=pixel): y[9] -> ysb; interior pixels -> xt ----
  {
    int r = t >> 4, cc = t & 15;
    unsigned int u[32];
#pragma unroll
    for (int c = 0; c < 32; ++c) u[c] = xs16[(c << 8) + t];
    float s[9];
#pragma unroll
    for (int dd = 0; dd < 9; ++dd) s[dd] = 0.f;
#pragma unroll
    for (int c = 0; c < 32; ++c) {
      float xf = bf16_to_f32(u[c]);
#pragma unroll
      for (int dd = 0; dd < 9; ++dd) s[dd] += xf * wks[c * 9 + dd];
    }
    if ((unsigned)(r - 1) < 14u) {
      int n = t - 16;
#pragma unroll
      for (int dd = 0; dd < 9; ++dd)
        ysb[dd * 224 + n] = (unsigned short)(bf16_rhu(s[dd]) >> 16);
    }
    if ((unsigned)(r - 4) < 8u && (unsigned)(cc - 4) < 8u) {
      int gn = (b << 14) + ((y0 + r - 4) << 7) + (x0 + cc - 4);
      unsigned int* dst = xt + gn * 16;
#pragma unroll
      for (int g4 = 0; g4 < 4; ++g4) {
        u32x4 d;
#pragma unroll
        for (int e = 0; e < 4; ++e) {
          int k2 = g4 * 4 + e;
          d[e] = __builtin_amdgcn_perm(u[2 * k2 + 1], u[2 * k2], 0x05040100u);
        }
        *reinterpret_cast<u32x4*>(dst + g4 * 4) = d;
      }
    }
  }
  __syncthreads();

  // ---- phase 2: as_[pos][px] = 1 + sigmoid(bk + sum_valid y) ----
#pragma unroll 1
  for (int it = 0; it < 13; ++it) {
    int f = it * 256 + t;
    if (f < 3136) {
      int pos = f >> 6;
      int px = f & 63;
      int py = px >> 3, pxl = px & 7;
      int i = pos / 7, j = pos - i * 7;
      float s = wks[288];
#pragma unroll
      for (int di = 0; di < 3; ++di) {
        int ii = i + di - 1;
        if ((unsigned)ii >= 7u) continue;
#pragma unroll
        for (int dj = 0; dj < 3; ++dj) {
          int jj = j + dj - 1;
          if ((unsigned)jj >= 7u) continue;
          s += bf16_to_f32(
              (unsigned int)ysb[(di * 3 + dj) * 224 + (py + ii) * 16 + pxl + jj + 1]);
        }
      }
      as_[pos * 68 + px] = 1.f + 1.f / (1.f + expf(-s));
    }
  }
  __syncthreads();

  // ---- phase 2.5: att_out (n-major, coalesced runs) + gt (tap-major) ----
#pragma unroll 1
  for (int it = 0; it < 13; ++it) {
    int f = it * 256 + t;
    if (f < 3136) {
      int row = f / 392;
      int rem = f - row * 392;
      int pxl2 = rem / 49;
      int pos2 = rem - pxl2 * 49;
      long base = ((long)(b << 14) + ((y0 + row) << 7) + x0) * 49;
      att_out[base + rem] = as_[pos2 * 68 + (row << 3) + pxl2] - 1.f;

      int pos = f >> 6, px = f & 63;
      int py = px >> 3, pxl = px & 7;
      gt[pos * NPIX + (b << 14) + ((y0 + py) << 7) + x0 + pxl] = as_[pos * 68 + px];
    }
  }
}

// GEMM kernel: 1024 blocks x 256 threads. block = (m-chunk of 64 px) x (o-half).
// B-half (49 KB) staged in LDS once; A read straight from xt (tap shift = n-offset).
__global__ __launch_bounds__(256) void gemm_kernel(
    const unsigned int* __restrict__ xt, const float* __restrict__ gt,
    const unsigned int* __restrict__ w3f, const float* __restrict__ b3,
    float* __restrict__ out) {
  __shared__ __align__(16) unsigned int bL[12544];   // 50,176 B

  int t = threadIdx.x;
  int oh = blockIdx.x & 1, bm = blockIdx.x >> 1;

  // stage this o-half's 49 B-fragments (u32x4 k -> [ij][lane])
#pragma unroll 1
  for (int it = 0; it < 13; ++it) {
    int k = it * 256 + t;
    if (k < 3136) {
      int ij = k >> 6, ln = k & 63;
      u32x4 v = *reinterpret_cast<const u32x4*>(w3f + ((ij * 128 + oh * 64 + ln) << 2));
      *reinterpret_cast<u32x4*>(bL + (k << 2)) = v;
    }
  }

  int wv = t >> 6, lane = t & 63;
  int ml = lane & 15, q = lane >> 4;
  int n0 = bm * 64 + wv * 16;          // wave's 16-pixel m-tile (one image row)
  int b = n0 >> 14;
  int p0 = n0 & 16383;
  int h0 = p0 >> 7, w0 = p0 & 127;
  float b3v = b3[oh * 16 + ml];
  f32x4 acc = {0.f, 0.f, 0.f, 0.f};
  __syncthreads();

#pragma unroll 1
  for (int i = 0; i < 7; ++i) {
    int hh = h0 + i - 3;
    if ((unsigned)hh >= 128u) continue;        // zero-pad row: contributes 0
    int nrow = (b << 14) + (hh << 7);
#pragma unroll
    for (int j = 0; j < 7; ++j) {
      int ij = i * 7 + j;
      int wl = w0 + ml + j - 3;
      bool okw = (unsigned)wl < 128u;          // per-lane w-edge mask
      int nn = okw ? (nrow + wl) : n0;         // safe in-bounds address
      u32x4 bw = *reinterpret_cast<const u32x4*>(bL + ((ij * 64 + lane) << 2));
      u32x4 araw = *reinterpret_cast<const u32x4*>(xt + nn * 16 + (q << 2));
      if (!okw) { araw[0] = 0; araw[1] = 0; araw[2] = 0; araw[3] = 0; }
      f32x4 gv = *reinterpret_cast<const f32x4*>(gt + ij * NPIX + n0 + (q << 2));
      f32x4 z = {0.f, 0.f, 0.f, 0.f};
      f32x4 P = __builtin_amdgcn_mfma_f32_16x16x32_bf16(
          __builtin_bit_cast(bf16x8, araw), __builtin_bit_cast(bf16x8, bw), z, 0, 0, 0);
#pragma unroll
      for (int r = 0; r < 4; ++r) acc[r] += gv[r] * P[r];
    }
  }

  __syncthreads();                              // all B reads done; reuse bL
  float* sc = reinterpret_cast<float*>(bL) + wv * 272;
#pragma unroll
  for (int r = 0; r < 4; ++r)
    sc[ml * 17 + (q << 2) + r] = acc[r] + b3v;  // D: col=ml(o'), row=q*4+r(px)
  // same-wave LDS readback (compiler orders via lgkmcnt; no cross-wave sharing)
#pragma unroll
  for (int pp = 0; pp < 4; ++pp) {
    int od = (pp << 2) + q;                     // o' 0..15
    out[((long)b << 19) + ((oh * 16 + od) << 14) + p0 + ml] = sc[od * 17 + ml];
  }
}

extern "C" void kernel_launch(void* const* d_in, const int* in_sizes, int n_in,
                              void* d_out, int out_size, void* d_ws, size_t ws_size,
                              hipStream_t stream) {
  const float* x  = (const float*)d_in[0];
  const float* w1 = (const float*)d_in[1];
  const float* b1 = (const float*)d_in[2];
  const float* w2 = (const float*)d_in[3];
  const float* b2 = (const float*)d_in[4];
  const float* w3 = (const float*)d_in[5];
  const float* b3 = (const float*)d_in[6];

  float* out = (float*)d_out;
  float* att_out = out + OUT0;

  char* ws = (char*)d_ws;
  float* wk = (float*)ws;                                  // 289 f32   @ 0
  unsigned int* w3f = (unsigned int*)(ws + 4096);          // 100,352 B @ 4 KiB
  unsigned int* xt  = (unsigned int*)(ws + 131072);        // 2 MiB     @ 128 KiB
  float* gt = (float*)(ws + 131072 + 2097152);             // 6.4 MB

  prep_kernel<<<100, 256, 0, stream>>>(w1, b1, w2, b2, w3, wk, w3f);
  att_kernel<<<512, 256, 0, stream>>>(x, wk, att_out, gt, xt);
  gemm_kernel<<<1024, 256, 0, stream>>>(xt, gt, w3f, b3, out);
}

// Round 8
// 98.819 us; speedup vs baseline: 1.2127x; 1.2127x over previous
//
#include <hip/hip_runtime.h>
#include <math.h>

typedef __attribute__((ext_vector_type(8))) short bf16x8;
typedef __attribute__((ext_vector_type(4))) float f32x4;
typedef __attribute__((ext_vector_type(4))) unsigned int u32x4;
typedef __attribute__((ext_vector_type(2))) unsigned int u32x2;

namespace {
constexpr int OUT0 = 2 * 32 * 16384;  // offset of att_mp inside d_out
}

// f32 -> bf16 RNE (pre-shift: result in high 16 bits)
__device__ __forceinline__ unsigned int bf16_rne(float f) {
  unsigned int u = __builtin_bit_cast(unsigned int, f);
  return u + 0x7fffu + ((u >> 16) & 1u);
}
// f32 -> bf16 round-half-up (1 VALU; tie-bias only)
__device__ __forceinline__ unsigned int bf16_rhu(float f) {
  return __builtin_bit_cast(unsigned int, f) + 0x8000u;
}
__device__ __forceinline__ unsigned int pack_rne(float lo, float hi) {
  return __builtin_amdgcn_perm(bf16_rne(hi), bf16_rne(lo), 0x07060302u);
}
__device__ __forceinline__ unsigned int pack_rhu(float lo, float hi) {
  return __builtin_amdgcn_perm(bf16_rhu(hi), bf16_rhu(lo), 0x07060302u);
}
__device__ __forceinline__ float bf16_to_f32(unsigned int u16v) {
  return __builtin_bit_cast(float, u16v << 16);
}

// Prep: (a) pack w3 into per-lane bf16 B-fragments for mfma_f32_16x16x32_bf16:
//   u32x4 index = ij*128 + oh*64 + lane; dword d: B[k0][o],B[k0+1][o],
//   k(=c) = (lane>>4)*8 + 2d, o = oh*16 + (lane&15).
// (b) wk[c*9+dd] = sum_o w2[o]*w1[o,c,dd]; wk[288] = w2.b1 + b2.
__global__ __launch_bounds__(256) void prep_kernel(
    const float* __restrict__ w1, const float* __restrict__ b1,
    const float* __restrict__ w2, const float* __restrict__ b2,
    const float* __restrict__ w3,
    float* __restrict__ wk, unsigned int* __restrict__ w3f) {
  int t = threadIdx.x, blk = blockIdx.x;
  if (blk < 98) {
    int f = blk * 256 + t;          // dword index, f < 25088
    int d = f & 3;
    int lane = (f >> 2) & 63;
    int nt = (f >> 8) & 1;
    int ij = f >> 9;                // 0..48
    int o = nt * 16 + (lane & 15);
    int k0 = ((lane >> 4) << 3) + 2 * d;
    float f0 = w3[o * 1568 + k0 * 49 + ij];
    float f1 = w3[o * 1568 + (k0 + 1) * 49 + ij];
    w3f[f] = pack_rne(f0, f1);
  } else {
    int k = (blk - 98) * 256 + t;
    if (k < 288) {
      int c = k / 9, r = k - c * 9;
      float s = 0.f;
#pragma unroll
      for (int o = 0; o < 32; ++o) s += w2[o] * w1[o * 288 + c * 9 + r];
      wk[k] = s;
    } else if (k == 288) {
      float s = b2[0];
#pragma unroll
      for (int o = 0; o < 32; ++o) s += w2[o] * b1[o];
      wk[288] = s;
    }
  }
}

// Fused kernel: block = (tile, o-half). 1024 blocks x 256 threads (4 waves).
// LDS 39.5 KB -> 4 blocks/CU; __launch_bounds__(256,4) caps VGPR at 128.
__global__ __launch_bounds__(256, 4) void fused_kernel(
    const float* __restrict__ x, const float* __restrict__ wk,
    const unsigned int* __restrict__ w3f, const float* __restrict__ b3,
    float* __restrict__ out, float* __restrict__ att_out) {
  // regA: phases 1-1b = planar bf16 x [c*256+sp]; phases 2+ = g-tile as_.
  __shared__ __align__(16) char regA[16384];
  unsigned short* xs16 = (unsigned short*)regA;
  float* as_ = (float*)regA;                       // as_[pos*68+px] = 1+att
  __shared__ __align__(16) unsigned short xh[224 * 40];  // bf16 x [sp'][c], rows 1..14
  __shared__ unsigned short ysb[9 * 224];          // bf16 y[dd][(r-1)*16+cc]
  __shared__ float wks[289];                       // total 39,492 B

  int t = threadIdx.x;
  int bi = blockIdx.x;
  int oh = bi & 1;                   // o-half of this block
  int tb = bi >> 1;
  int b = tb >> 8;
  int tile = tb & 255;
  int y0 = (tile >> 4) << 3, x0 = (tile & 15) << 3;
  const float* xb = x + ((long)b << 19);

  for (int k = t; k < 289; k += 256) wks[k] = wk[k];

  // ---- phase 1: global f32x4 -> bf16 -> planar xs16 (conflict-free b64) ----
#pragma unroll
  for (int it = 0; it < 8; ++it) {
    int idx = it * 256 + t;
    int c = idx >> 6;
    int r64 = idx & 63;
    int row = r64 >> 2, seg = r64 & 3;
    int gy = y0 + row - 4;
    int gxs = x0 + (seg << 2) - 4;
    f32x4 v = {0.f, 0.f, 0.f, 0.f};
    if ((unsigned)gy < 128u && (unsigned)gxs < 128u)
      v = *reinterpret_cast<const f32x4*>(xb + (c << 14) + (gy << 7) + gxs);
    u32x2 p;
    p[0] = pack_rhu(v[0], v[1]);
    p[1] = pack_rhu(v[2], v[3]);
    *reinterpret_cast<u32x2*>(reinterpret_cast<unsigned int*>(xs16) +
                              (c << 7) + (r64 << 1)) = p;
  }
  __syncthreads();

  // ---- phase 1b (thread=pixel): y[9] -> ysb; transpose-pack -> xh ----
  {
    int r = t >> 4;
    bool inner = (unsigned)(r - 1) < 14u;   // rows 1..14 are the used window
    int n = t - 16;
    unsigned int u[32];
#pragma unroll
    for (int c = 0; c < 32; ++c) u[c] = xs16[(c << 8) + t];
    float s[9];
#pragma unroll
    for (int dd = 0; dd < 9; ++dd) s[dd] = 0.f;
#pragma unroll
    for (int c = 0; c < 32; ++c) {
      float xf = bf16_to_f32(u[c]);
#pragma unroll
      for (int dd = 0; dd < 9; ++dd) s[dd] += xf * wks[c * 9 + dd];
    }
    if (inner) {
#pragma unroll
      for (int dd = 0; dd < 9; ++dd)
        ysb[dd * 224 + n] = (unsigned short)(bf16_rhu(s[dd]) >> 16);
      unsigned int* xhd = reinterpret_cast<unsigned int*>(xh) + n * 20;
#pragma unroll
      for (int g4 = 0; g4 < 4; ++g4) {
        u32x4 d;
#pragma unroll
        for (int e = 0; e < 4; ++e) {
          int k2 = g4 * 4 + e;
          d[e] = __builtin_amdgcn_perm(u[2 * k2 + 1], u[2 * k2], 0x05040100u);
        }
        *reinterpret_cast<u32x4*>(xhd + g4 * 4) = d;
      }
    }
  }
  __syncthreads();

  // ---- phase 2: as_[pos][px] = 1 + sigmoid(bk + sum_valid y) ----
#pragma unroll 1
  for (int it = 0; it < 13; ++it) {
    int f = it * 256 + t;
    if (f < 3136) {
      int pos = f >> 6;               // wave-uniform
      int px = f & 63;
      int py = px >> 3, pxl = px & 7;
      int i = pos / 7, j = pos - i * 7;
      float s = wks[288];
#pragma unroll
      for (int di = 0; di < 3; ++di) {
        int ii = i + di - 1;
        if ((unsigned)ii >= 7u) continue;
#pragma unroll
        for (int dj = 0; dj < 3; ++dj) {
          int jj = j + dj - 1;
          if ((unsigned)jj >= 7u) continue;
          s += bf16_to_f32(
              (unsigned int)ysb[(di * 3 + dj) * 224 + (py + ii) * 16 + pxl + jj + 1]);
        }
      }
      float e = __builtin_amdgcn_exp2f(s * -1.44269504088896f);
      as_[pos * 68 + px] = 1.f + __builtin_amdgcn_rcpf(1.f + e);
    }
  }
  __syncthreads();

  // ---- phase 2.5: att_out (oh==0 blocks only; coalesced 392-float runs) ----
  if (oh == 0) {
#pragma unroll 1
    for (int it = 0; it < 13; ++it) {
      int f = it * 256 + t;
      if (f < 3136) {
        int row = f / 392;
        int rem = f - row * 392;
        int pxl = rem / 49;
        int pos = rem - pxl * 49;
        long base = ((long)(b << 14) + ((y0 + row) << 7) + x0) * 49;
        att_out[base + rem] = as_[pos * 68 + (row << 3) + pxl] - 1.f;
      }
    }
  }

  // ---- phase 3: wave = m-tile; this block's oh; 1 MFMA per tap ----
  int wv = t >> 6, lane = t & 63;
  int ml = lane & 15, q = lane >> 4;
  int px = wv * 16 + ml;
  int py = px >> 3, pxl = px & 7;
  f32x4 acc = {0.f, 0.f, 0.f, 0.f};
  const u32x4* bp = reinterpret_cast<const u32x4*>(w3f) + oh * 64 + lane;
#pragma unroll 1
  for (int i = 0; i < 7; ++i) {
    int nb = (py + i) * 16 + pxl + 1;
#pragma unroll
    for (int j = 0; j < 7; ++j) {
      int ij = i * 7 + j;
      u32x4 bw = bp[ij * 128];
      bf16x8 af = *reinterpret_cast<const bf16x8*>(&xh[(nb + j) * 40 + (q << 3)]);
      f32x4 gv = *reinterpret_cast<const f32x4*>(&as_[ij * 68 + wv * 16 + (q << 2)]);
      f32x4 z = {0.f, 0.f, 0.f, 0.f};
      f32x4 P = __builtin_amdgcn_mfma_f32_16x16x32_bf16(
          af, __builtin_bit_cast(bf16x8, bw), z, 0, 0, 0);
#pragma unroll
      for (int r = 0; r < 4; ++r) acc[r] += gv[r] * P[r];
    }
  }

  // ---- epilogue: direct f32x4 store. Lane holds o=oh*16+ml, px=wv*16+q*4+r;
  // the 4 px of one lane stay inside one 8-px image row. No LDS, no barrier.
  {
    float bv = b3[(oh << 4) + ml];
    f32x4 res;
#pragma unroll
    for (int r = 0; r < 4; ++r) res[r] = acc[r] + bv;
    int pyd = (wv << 1) + (q >> 1);
    int pxd = (q & 1) << 2;
    float* dst = out + ((long)b << 19) + (((oh << 4) + ml) << 14) +
                 ((y0 + pyd) << 7) + x0 + pxd;
    *reinterpret_cast<f32x4*>(dst) = res;
  }
}

extern "C" void kernel_launch(void* const* d_in, const int* in_sizes, int n_in,
                              void* d_out, int out_size, void* d_ws, size_t ws_size,
                              hipStream_t stream) {
  const float* x  = (const float*)d_in[0];
  const float* w1 = (const float*)d_in[1];
  const float* b1 = (const float*)d_in[2];
  const float* w2 = (const float*)d_in[3];
  const float* b2 = (const float*)d_in[4];
  const float* w3 = (const float*)d_in[5];
  const float* b3 = (const float*)d_in[6];

  float* out = (float*)d_out;
  float* att_out = out + OUT0;
  float* wk = (float*)d_ws;                                // 289 floats
  unsigned int* w3f = (unsigned int*)((char*)d_ws + 4096); // 25088 dwords

  prep_kernel<<<100, 256, 0, stream>>>(w1, b1, w2, b2, w3, wk, w3f);
  fused_kernel<<<1024, 256, 0, stream>>>(x, wk, w3f, b3, out, att_out);
}

// Round 9
// 90.849 us; speedup vs baseline: 1.3191x; 1.0877x over previous
//
#include <hip/hip_runtime.h>
#include <math.h>

typedef __attribute__((ext_vector_type(8))) short bf16x8;
typedef __attribute__((ext_vector_type(4))) float f32x4;
typedef __attribute__((ext_vector_type(4))) unsigned int u32x4;
typedef __attribute__((ext_vector_type(2))) unsigned int u32x2;

namespace {
constexpr int OUT0 = 2 * 32 * 16384;  // offset of att_mp inside d_out
}

// f32 -> bf16 RNE (pre-shift: result in high 16 bits)
__device__ __forceinline__ unsigned int bf16_rne(float f) {
  unsigned int u = __builtin_bit_cast(unsigned int, f);
  return u + 0x7fffu + ((u >> 16) & 1u);
}
// f32 -> bf16 round-half-up (1 VALU; tie-bias only)
__device__ __forceinline__ unsigned int bf16_rhu(float f) {
  return __builtin_bit_cast(unsigned int, f) + 0x8000u;
}
__device__ __forceinline__ unsigned int pack_rne(float lo, float hi) {
  return __builtin_amdgcn_perm(bf16_rne(hi), bf16_rne(lo), 0x07060302u);
}
__device__ __forceinline__ unsigned int pack_rhu(float lo, float hi) {
  return __builtin_amdgcn_perm(bf16_rhu(hi), bf16_rhu(lo), 0x07060302u);
}
__device__ __forceinline__ float bf16_to_f32(unsigned int u16v) {
  return __builtin_bit_cast(float, u16v << 16);
}

// Prep: (a) pack w3 into per-lane bf16 B-fragments for mfma_f32_16x16x32_bf16:
//   u32x4 index = ij*128 + oh*64 + lane; dword d: B[k0][o],B[k0+1][o],
//   k(=c) = (lane>>4)*8 + 2d, o = oh*16 + (lane&15).
// (b) wk[c*9+dd] = sum_o w2[o]*w1[o,c,dd]; wk[288] = w2.b1 + b2.
__global__ __launch_bounds__(256) void prep_kernel(
    const float* __restrict__ w1, const float* __restrict__ b1,
    const float* __restrict__ w2, const float* __restrict__ b2,
    const float* __restrict__ w3,
    float* __restrict__ wk, unsigned int* __restrict__ w3f) {
  int t = threadIdx.x, blk = blockIdx.x;
  if (blk < 98) {
    int f = blk * 256 + t;          // dword index, f < 25088
    int d = f & 3;
    int lane = (f >> 2) & 63;
    int nt = (f >> 8) & 1;
    int ij = f >> 9;                // 0..48
    int o = nt * 16 + (lane & 15);
    int k0 = ((lane >> 4) << 3) + 2 * d;
    float f0 = w3[o * 1568 + k0 * 49 + ij];
    float f1 = w3[o * 1568 + (k0 + 1) * 49 + ij];
    w3f[f] = pack_rne(f0, f1);
  } else {
    int k = (blk - 98) * 256 + t;
    if (k < 288) {
      int c = k / 9, r = k - c * 9;
      float s = 0.f;
#pragma unroll
      for (int o = 0; o < 32; ++o) s += w2[o] * w1[o * 288 + c * 9 + r];
      wk[k] = s;
    } else if (k == 288) {
      float s = b2[0];
#pragma unroll
      for (int o = 0; o < 32; ++o) s += w2[o] * b1[o];
      wk[288] = s;
    }
  }
}

// Fused kernel: one 8x8 pixel tile per block; 512 blocks x 512 threads (8 waves).
// After phase 2: waves 0-3 run the GEMM (full 32-o per m-tile, halving phase-3
// LDS reads vs the wave-pair scheme); waves 4-7 do att_out stores concurrently.
__global__ __launch_bounds__(512, 4) void fused_kernel(
    const float* __restrict__ x, const float* __restrict__ wk,
    const unsigned int* __restrict__ w3f, const float* __restrict__ b3,
    float* __restrict__ out, float* __restrict__ att_out) {
  // regA: phases 1-1b = planar bf16 x [c*256+sp]; phases 2+ = g-tile as_.
  __shared__ __align__(16) char regA[16384];
  unsigned short* xs16 = (unsigned short*)regA;
  float* as_ = (float*)regA;                       // as_[pos*68+px] = 1+att
  __shared__ __align__(16) unsigned short xh[224 * 40];  // bf16 x [sp'][c], rows 1..14
  __shared__ unsigned short ysb[9 * 224];          // bf16 y[dd][(r-1)*16+cc]
  __shared__ float wks[289];                       // total 39,492 B

  int t = threadIdx.x;
  int bi = blockIdx.x;
  int b = bi >> 8;
  int tile = bi & 255;
  int y0 = (tile >> 4) << 3, x0 = (tile & 15) << 3;
  const float* xb = x + ((long)b << 19);

  for (int k = t; k < 289; k += 512) wks[k] = wk[k];

  // ---- phase 1: global f32x4 -> bf16 -> planar xs16 (conflict-free b64) ----
#pragma unroll
  for (int it = 0; it < 4; ++it) {
    int idx = it * 512 + t;
    int c = idx >> 6;                 // wave-uniform
    int r64 = idx & 63;               // 4-pixel segment id; sp = 4*r64
    int row = r64 >> 2, seg = r64 & 3;
    int gy = y0 + row - 4;
    int gxs = x0 + (seg << 2) - 4;
    f32x4 v = {0.f, 0.f, 0.f, 0.f};
    if ((unsigned)gy < 128u && (unsigned)gxs < 128u)
      v = *reinterpret_cast<const f32x4*>(xb + (c << 14) + (gy << 7) + gxs);
    u32x2 p;
    p[0] = pack_rhu(v[0], v[1]);
    p[1] = pack_rhu(v[2], v[3]);
    *reinterpret_cast<u32x2*>(reinterpret_cast<unsigned int*>(xs16) +
                              (c << 7) + (r64 << 1)) = p;
  }
  __syncthreads();

  // ---- phase 1b (t<256, thread=pixel): y[9] -> ysb; transpose-pack -> xh ----
  if (t < 256) {
    int r = t >> 4;
    bool inner = (unsigned)(r - 1) < 14u;   // rows 1..14 are the used window
    int n = t - 16;
    unsigned int u[32];
#pragma unroll
    for (int c = 0; c < 32; ++c) u[c] = xs16[(c << 8) + t];
    float s[9];
#pragma unroll
    for (int dd = 0; dd < 9; ++dd) s[dd] = 0.f;
#pragma unroll
    for (int c = 0; c < 32; ++c) {
      float xf = bf16_to_f32(u[c]);
#pragma unroll
      for (int dd = 0; dd < 9; ++dd) s[dd] += xf * wks[c * 9 + dd];
    }
    if (inner) {
#pragma unroll
      for (int dd = 0; dd < 9; ++dd)
        ysb[dd * 224 + n] = (unsigned short)(bf16_rhu(s[dd]) >> 16);
      unsigned int* xhd = reinterpret_cast<unsigned int*>(xh) + n * 20;
#pragma unroll
      for (int g4 = 0; g4 < 4; ++g4) {
        u32x4 d;
#pragma unroll
        for (int e = 0; e < 4; ++e) {
          int k2 = g4 * 4 + e;
          d[e] = __builtin_amdgcn_perm(u[2 * k2 + 1], u[2 * k2], 0x05040100u);
        }
        *reinterpret_cast<u32x4*>(xhd + g4 * 4) = d;
      }
    }
  }
  __syncthreads();

  // ---- phase 2: as_[pos][px] = 1 + sigmoid(bk + sum_valid y) ----
#pragma unroll 1
  for (int it = 0; it < 7; ++it) {
    int f = it * 512 + t;
    if (f < 3136) {
      int pos = f >> 6;               // wave-uniform
      int px = f & 63;
      int py = px >> 3, pxl = px & 7;
      int i = pos / 7, j = pos - i * 7;
      float s = wks[288];
#pragma unroll
      for (int di = 0; di < 3; ++di) {
        int ii = i + di - 1;
        if ((unsigned)ii >= 7u) continue;
#pragma unroll
        for (int dj = 0; dj < 3; ++dj) {
          int jj = j + dj - 1;
          if ((unsigned)jj >= 7u) continue;
          s += bf16_to_f32(
              (unsigned int)ysb[(di * 3 + dj) * 224 + (py + ii) * 16 + pxl + jj + 1]);
        }
      }
      float e = __builtin_amdgcn_exp2f(s * -1.44269504088896f);
      as_[pos * 68 + px] = 1.f + __builtin_amdgcn_rcpf(1.f + e);
    }
  }
  __syncthreads();

  int wv = t >> 6, lane = t & 63;
  if (wv >= 4) {
    // ---- waves 4-7: att_out stores (coalesced 392-float runs per pixel row),
    // concurrent with the GEMM below ----
    int tt = t - 256;
#pragma unroll 1
    for (int it = 0; it < 13; ++it) {
      int f = it * 256 + tt;
      if (f < 3136) {
        int row = f / 392;
        int rem = f - row * 392;
        int pxl = rem / 49;
        int pos = rem - pxl * 49;
        long base = ((long)(b << 14) + ((y0 + row) << 7) + x0) * 49;
        att_out[base + rem] = as_[pos * 68 + (row << 3) + pxl] - 1.f;
      }
    }
  } else {
    // ---- waves 0-3: GEMM. wave = m-tile (16 px), both o-halves per tap ----
    int ml = lane & 15, q = lane >> 4;
    int px = (wv << 4) + ml;
    int py = px >> 3, pxl = px & 7;
    f32x4 acc0 = {0.f, 0.f, 0.f, 0.f}, acc1 = {0.f, 0.f, 0.f, 0.f};
    const u32x4* bp = reinterpret_cast<const u32x4*>(w3f) + lane;
#pragma unroll 1
    for (int i = 0; i < 7; ++i) {
      int nb = (py + i) * 16 + pxl + 1;
#pragma unroll
      for (int j = 0; j < 7; ++j) {
        int ij = i * 7 + j;
        u32x4 bw0 = bp[ij * 128];
        u32x4 bw1 = bp[ij * 128 + 64];
        bf16x8 af = *reinterpret_cast<const bf16x8*>(&xh[(nb + j) * 40 + (q << 3)]);
        f32x4 gv = *reinterpret_cast<const f32x4*>(&as_[ij * 68 + (wv << 4) + (q << 2)]);
        f32x4 z = {0.f, 0.f, 0.f, 0.f};
        f32x4 P0 = __builtin_amdgcn_mfma_f32_16x16x32_bf16(
            af, __builtin_bit_cast(bf16x8, bw0), z, 0, 0, 0);
        f32x4 P1 = __builtin_amdgcn_mfma_f32_16x16x32_bf16(
            af, __builtin_bit_cast(bf16x8, bw1), z, 0, 0, 0);
#pragma unroll
        for (int r = 0; r < 4; ++r) {
          acc0[r] += gv[r] * P0[r];
          acc1[r] += gv[r] * P1[r];
        }
      }
    }
    // ---- epilogue: direct f32x4 stores. Lane: o=ml (acc0) / 16+ml (acc1);
    // px = wv*16 + q*4 + r, all 4 within one 8-px image row. No barrier. ----
    float bv0 = b3[ml], bv1 = b3[16 + ml];
    f32x4 r0, r1;
#pragma unroll
    for (int r = 0; r < 4; ++r) { r0[r] = acc0[r] + bv0; r1[r] = acc1[r] + bv1; }
    int pyd = (wv << 1) + (q >> 1);
    int pxd = (q & 1) << 2;
    float* dst = out + ((long)b << 19) + ((y0 + pyd) << 7) + x0 + pxd;
    *reinterpret_cast<f32x4*>(dst + (ml << 14)) = r0;
    *reinterpret_cast<f32x4*>(dst + ((16 + ml) << 14)) = r1;
  }
}

extern "C" void kernel_launch(void* const* d_in, const int* in_sizes, int n_in,
                              void* d_out, int out_size, void* d_ws, size_t ws_size,
                              hipStream_t stream) {
  const float* x  = (const float*)d_in[0];
  const float* w1 = (const float*)d_in[1];
  const float* b1 = (const float*)d_in[2];
  const float* w2 = (const float*)d_in[3];
  const float* b2 = (const float*)d_in[4];
  const float* w3 = (const float*)d_in[5];
  const float* b3 = (const float*)d_in[6];

  float* out = (float*)d_out;
  float* att_out = out + OUT0;
  float* wk = (float*)d_ws;                                // 289 floats
  unsigned int* w3f = (unsigned int*)((char*)d_ws + 4096); // 25088 dwords

  prep_kernel<<<100, 256, 0, stream>>>(w1, b1, w2, b2, w3, wk, w3f);
  fused_kernel<<<512, 512, 0, stream>>>(x, wk, w3f, b3, out, att_out);
}

// Round 10
// 90.612 us; speedup vs baseline: 1.3226x; 1.0026x over previous
//
#include <hip/hip_runtime.h>
#include <math.h>

typedef __attribute__((ext_vector_type(8))) short bf16x8;
typedef __attribute__((ext_vector_type(4))) float f32x4;
typedef __attribute__((ext_vector_type(4))) unsigned int u32x4;
typedef __attribute__((ext_vector_type(2))) unsigned int u32x2;

namespace {
constexpr int OUT0 = 2 * 32 * 16384;  // offset of att_mp inside d_out
}

// f32 -> bf16 RNE (pre-shift: result in high 16 bits)
__device__ __forceinline__ unsigned int bf16_rne(float f) {
  unsigned int u = __builtin_bit_cast(unsigned int, f);
  return u + 0x7fffu + ((u >> 16) & 1u);
}
// f32 -> bf16 round-half-up (1 VALU; tie-bias only)
__device__ __forceinline__ unsigned int bf16_rhu(float f) {
  return __builtin_bit_cast(unsigned int, f) + 0x8000u;
}
__device__ __forceinline__ unsigned int pack_rne(float lo, float hi) {
  return __builtin_amdgcn_perm(bf16_rne(hi), bf16_rne(lo), 0x07060302u);
}
__device__ __forceinline__ unsigned int pack_rhu(float lo, float hi) {
  return __builtin_amdgcn_perm(bf16_rhu(hi), bf16_rhu(lo), 0x07060302u);
}
__device__ __forceinline__ float bf16_to_f32(unsigned int u16v) {
  return __builtin_bit_cast(float, u16v << 16);
}

// Prep: (a) pack w3 into per-lane bf16 B-fragments for mfma_f32_16x16x32_bf16:
//   u32x4 index = ij*128 + oh*64 + lane; dword d: B[k0][o],B[k0+1][o],
//   k(=c) = (lane>>4)*8 + 2d, o = oh*16 + (lane&15).
// (b) wk[c*9+dd] = sum_o w2[o]*w1[o,c,dd]; wk[288] = w2.b1 + b2.
__global__ __launch_bounds__(256) void prep_kernel(
    const float* __restrict__ w1, const float* __restrict__ b1,
    const float* __restrict__ w2, const float* __restrict__ b2,
    const float* __restrict__ w3,
    float* __restrict__ wk, unsigned int* __restrict__ w3f) {
  int t = threadIdx.x, blk = blockIdx.x;
  if (blk < 98) {
    int f = blk * 256 + t;          // dword index, f < 25088
    int d = f & 3;
    int lane = (f >> 2) & 63;
    int nt = (f >> 8) & 1;
    int ij = f >> 9;                // 0..48
    int o = nt * 16 + (lane & 15);
    int k0 = ((lane >> 4) << 3) + 2 * d;
    float f0 = w3[o * 1568 + k0 * 49 + ij];
    float f1 = w3[o * 1568 + (k0 + 1) * 49 + ij];
    w3f[f] = pack_rne(f0, f1);
  } else {
    int k = (blk - 98) * 256 + t;
    if (k < 288) {
      int c = k / 9, r = k - c * 9;
      float s = 0.f;
#pragma unroll
      for (int o = 0; o < 32; ++o) s += w2[o] * w1[o * 288 + c * 9 + r];
      wk[k] = s;
    } else if (k == 288) {
      float s = b2[0];
#pragma unroll
      for (int o = 0; o < 32; ++o) s += w2[o] * b1[o];
      wk[288] = s;
    }
  }
}

// Fused kernel: one 4x8 interior tile per block (staged 12x16 + halo).
// 1024 blocks x 256 threads (4 waves) -> 4 independent blocks per CU.
// After phase 2: waves 0-1 = GEMM (16-px m-tile each, both o-halves);
// waves 2-3 = att_out stores, concurrent with the GEMM.
__global__ __launch_bounds__(256, 4) void fused_kernel(
    const float* __restrict__ x, const float* __restrict__ wk,
    const unsigned int* __restrict__ w3f, const float* __restrict__ b3,
    float* __restrict__ out, float* __restrict__ att_out) {
  // regA: phases 1-1b = planar bf16 x [c*192+sp] (12,288 B);
  //       phases 2+  = as_ g-tile [pos*36+px] (7,056 B), aliased.
  __shared__ __align__(16) char regA[12288];
  unsigned short* xs16 = (unsigned short*)regA;
  float* as_ = (float*)regA;
  __shared__ __align__(16) unsigned short xh[160 * 40];  // bf16 x [n2][c], rows 1..10
  __shared__ unsigned short ysb[9 * 160];                // bf16 y[dd][(r-1)*16+cc]
  __shared__ float wks[289];                             // total ~28.8 KB

  int t = threadIdx.x;
  int bi = blockIdx.x;
  int b = bi >> 9;
  int tb = bi & 511;
  int y0 = (tb >> 4) << 2;          // tile rows: 4
  int x0 = (tb & 15) << 3;          // tile cols: 8
  const float* xb = x + ((long)b << 19);

  for (int k = t; k < 289; k += 256) wks[k] = wk[k];

  // ---- phase 1: global f32x4 -> bf16 -> planar xs16. Staged 12 rows x 16
  // cols x 32 ch = 1536 f32x4 segments; geometry keeps segments fully in/out.
#pragma unroll
  for (int it = 0; it < 6; ++it) {
    int idx = it * 256 + t;
    int c = idx / 48;
    int r48 = idx - c * 48;
    int row = r48 >> 2, seg = r48 & 3;
    int gy = y0 + row - 4;
    int gxs = x0 + (seg << 2) - 4;
    f32x4 v = {0.f, 0.f, 0.f, 0.f};
    if ((unsigned)gy < 128u && (unsigned)gxs < 128u)
      v = *reinterpret_cast<const f32x4*>(xb + (c << 14) + (gy << 7) + gxs);
    u32x2 p;
    p[0] = pack_rhu(v[0], v[1]);
    p[1] = pack_rhu(v[2], v[3]);
    *reinterpret_cast<u32x2*>(reinterpret_cast<unsigned int*>(xs16) +
                              c * 96 + (r48 << 1)) = p;
  }
  __syncthreads();

  // ---- phase 1b (t<192, thread=staged pixel): y[9] -> ysb; pack -> xh ----
  if (t < 192) {
    int r = t >> 4;                        // staged row 0..11
    bool inner = (unsigned)(r - 1) < 10u;  // rows 1..10 are the used window
    int n = t - 16;                        // = (r-1)*16 + cc
    unsigned int u[32];
#pragma unroll
    for (int c = 0; c < 32; ++c) u[c] = xs16[c * 192 + t];
    float s[9];
#pragma unroll
    for (int dd = 0; dd < 9; ++dd) s[dd] = 0.f;
#pragma unroll
    for (int c = 0; c < 32; ++c) {
      float xf = bf16_to_f32(u[c]);
#pragma unroll
      for (int dd = 0; dd < 9; ++dd) s[dd] += xf * wks[c * 9 + dd];
    }
    if (inner) {
#pragma unroll
      for (int dd = 0; dd < 9; ++dd)
        ysb[dd * 160 + n] = (unsigned short)(bf16_rhu(s[dd]) >> 16);
      unsigned int* xhd = reinterpret_cast<unsigned int*>(xh) + n * 20;
#pragma unroll
      for (int g4 = 0; g4 < 4; ++g4) {
        u32x4 d;
#pragma unroll
        for (int e = 0; e < 4; ++e) {
          int k2 = g4 * 4 + e;
          d[e] = __builtin_amdgcn_perm(u[2 * k2 + 1], u[2 * k2], 0x05040100u);
        }
        *reinterpret_cast<u32x4*>(xhd + g4 * 4) = d;
      }
    }
  }
  __syncthreads();

  // ---- phase 2: as_[pos][px] = 1 + sigmoid(bk + sum_valid y), px<32 ----
#pragma unroll 1
  for (int it = 0; it < 7; ++it) {
    int f = it * 256 + t;
    if (f < 1568) {
      int pos = f >> 5;
      int px = f & 31;
      int py = px >> 3, pxl = px & 7;
      int i = pos / 7, j = pos - i * 7;
      float s = wks[288];
#pragma unroll
      for (int di = 0; di < 3; ++di) {
        int ii = i + di - 1;
        if ((unsigned)ii >= 7u) continue;
#pragma unroll
        for (int dj = 0; dj < 3; ++dj) {
          int jj = j + dj - 1;
          if ((unsigned)jj >= 7u) continue;
          s += bf16_to_f32(
              (unsigned int)ysb[(di * 3 + dj) * 160 + (py + ii) * 16 + pxl + jj + 1]);
        }
      }
      float e = __builtin_amdgcn_exp2f(s * -1.44269504088896f);
      as_[pos * 36 + px] = 1.f + __builtin_amdgcn_rcpf(1.f + e);
    }
  }
  __syncthreads();

  int wv = t >> 6, lane = t & 63;
  if (wv >= 2) {
    // ---- waves 2-3: att_out stores (contiguous 392-float run per image row),
    // concurrent with the GEMM below ----
    int tt = t - 128;
#pragma unroll 1
    for (int it = 0; it < 13; ++it) {
      int f = it * 128 + tt;
      if (f < 1568) {
        int row = f / 392;
        int rem = f - row * 392;
        int pxl = rem / 49;
        int pos = rem - pxl * 49;
        long base = ((long)(b << 14) + ((y0 + row) << 7) + x0) * 49;
        att_out[base + rem] = as_[pos * 36 + (row << 3) + pxl] - 1.f;
      }
    }
  } else {
    // ---- waves 0-1: GEMM. wave = 16-px m-tile, both o-halves per tap ----
    int ml = lane & 15, q = lane >> 4;
    int px = (wv << 4) + ml;
    int py = px >> 3, pxl = px & 7;
    f32x4 acc0 = {0.f, 0.f, 0.f, 0.f}, acc1 = {0.f, 0.f, 0.f, 0.f};
    const u32x4* bp = reinterpret_cast<const u32x4*>(w3f) + lane;
#pragma unroll 1
    for (int i = 0; i < 7; ++i) {
      int nb = (py + i) * 16 + pxl + 1;    // xh row base for this tap row
#pragma unroll
      for (int j = 0; j < 7; ++j) {
        int ij = i * 7 + j;
        u32x4 bw0 = bp[ij * 128];
        u32x4 bw1 = bp[ij * 128 + 64];
        bf16x8 af = *reinterpret_cast<const bf16x8*>(&xh[(nb + j) * 40 + (q << 3)]);
        f32x4 gv = *reinterpret_cast<const f32x4*>(&as_[ij * 36 + (wv << 4) + (q << 2)]);
        f32x4 z = {0.f, 0.f, 0.f, 0.f};
        f32x4 P0 = __builtin_amdgcn_mfma_f32_16x16x32_bf16(
            af, __builtin_bit_cast(bf16x8, bw0), z, 0, 0, 0);
        f32x4 P1 = __builtin_amdgcn_mfma_f32_16x16x32_bf16(
            af, __builtin_bit_cast(bf16x8, bw1), z, 0, 0, 0);
#pragma unroll
        for (int r = 0; r < 4; ++r) {
          acc0[r] += gv[r] * P0[r];
          acc1[r] += gv[r] * P1[r];
        }
      }
    }
    // ---- epilogue: direct f32x4 stores. Lane: o=ml (acc0) / 16+ml (acc1);
    // px = wv*16 + q*4 + r, all 4 within one 8-px image row. No barrier. ----
    float bv0 = b3[ml], bv1 = b3[16 + ml];
    f32x4 r0, r1;
#pragma unroll
    for (int r = 0; r < 4; ++r) { r0[r] = acc0[r] + bv0; r1[r] = acc1[r] + bv1; }
    int pyd = (wv << 1) + (q >> 1);
    int pxd = (q & 1) << 2;
    float* dst = out + ((long)b << 19) + ((y0 + pyd) << 7) + x0 + pxd;
    *reinterpret_cast<f32x4*>(dst + (ml << 14)) = r0;
    *reinterpret_cast<f32x4*>(dst + ((16 + ml) << 14)) = r1;
  }
}

extern "C" void kernel_launch(void* const* d_in, const int* in_sizes, int n_in,
                              void* d_out, int out_size, void* d_ws, size_t ws_size,
                              hipStream_t stream) {
  const float* x  = (const float*)d_in[0];
  const float* w1 = (const float*)d_in[1];
  const float* b1 = (const float*)d_in[2];
  const float* w2 = (const float*)d_in[3];
  const float* b2 = (const float*)d_in[4];
  const float* w3 = (const float*)d_in[5];
  const float* b3 = (const float*)d_in[6];

  float* out = (float*)d_out;
  float* att_out = out + OUT0;
  float* wk = (float*)d_ws;                                // 289 floats
  unsigned int* w3f = (unsigned int*)((char*)d_ws + 4096); // 25088 dwords

  prep_kernel<<<100, 256, 0, stream>>>(w1, b1, w2, b2, w3, wk, w3f);
  fused_kernel<<<1024, 256, 0, stream>>>(x, wk, w3f, b3, out, att_out);
}